// Round 1
// 222.133 us; speedup vs baseline: 1.0640x; 1.0640x over previous
//
#include <hip/hip_runtime.h>
#include <hip/hip_bf16.h>

// out[s,b,o] = sum_h in[s,b,h] * w[o,h]
// A = [M=8192, K=1024] fp32, W = [N=4096, K=1024] fp32 (B^T layout), C = [M,N] fp32.
//
// Round 2 -> 3: port to the 256x256 8-phase template (T3+T4 counted-vmcnt pipeline,
// T5 setprio, T2 swizzle carried over from round 2's zero-conflict XOR-8 scheme).
// Structure: 8 waves (2M x 4N), BK=64, LDS 128 KiB = 2 bufs x (A 256x64 + B 256x64) bf16.
// Per phase: {ds_read subtile | issue one 16KB stage-unit} -> s_barrier -> lgkmcnt(0)
// -> setprio(1) 16 MFMA setprio(0) -> s_barrier.  vmcnt(4) ONLY at phases 4 and 8.
//
// Stage-unit ledger (E = even tile in buf0, O = odd tile in buf1; quadrant order
// q1=(mh0,nh0) q2=(mh0,nh1) q3=(mh1,nh1) q4=(mh1,nh0); units u1=A.mh0 u2=B.nh0
// u3=A.mh1 u4=B.nh1):
//   ph1 E.q1  reads A0,B0   stages O.u2    (buf1.Bnh0 last read prev ph5)
//   ph2 E.q2  reads B1      stages O.u3    (buf1.Amh1 last read prev ph7)
//   ph3 E.q3  reads A1      stages E+2.u1  (buf0.Amh0 last read ph1)
//   ph4 E.q4  reads -       stages E+2.u4  (buf0.Bnh1 last read ph2)   GATE vmcnt(4)
//   ph5 O.q1  reads A0,B0   stages E+2.u3  (buf0.Amh1 last read ph3)
//   ph6 O.q2  reads B1      stages E+2.u2  (buf0.Bnh0 last read ph1)
//   ph7 O.q3  reads A1      stages E+3.u1  (buf1.Amh0 last read ph5)
//   ph8 O.q4  reads -       stages E+3.u4  (buf1.Bnh1 last read ph6)   GATE vmcnt(4)
// Every stage is >=2 barrier-separated phases after its region's last ds_read.
// At each gate, the next tile's 4 units sit 3..6-from-last in issue order, so
// vmcnt(4) (= 2 units in flight) guarantees them landed. Tail iterations clamp the
// stage k0 to the last tile (writes garbage into already-consumed regions; never read).

typedef __bf16 bf16x8_t __attribute__((ext_vector_type(8)));
typedef float f32x4_t __attribute__((ext_vector_type(4)));

constexpr int M = 8192;
constexpr int N = 4096;
constexpr int K = 1024;
constexpr int BM = 256;
constexpr int BN = 256;
constexpr int BK = 64;

// ---------------- fp32 -> bf16 convert, both tensors in one launch ----------
__global__ __launch_bounds__(256) void cvt_f32_bf16(const float* __restrict__ a,
                                                    const float* __restrict__ w,
                                                    __bf16* __restrict__ a_bf,
                                                    __bf16* __restrict__ w_bf) {
    size_t i = ((size_t)blockIdx.x * 256 + threadIdx.x) * 8;
    const float* src;
    __bf16* dst;
    if (i < (size_t)M * K) {
        src = a + i;
        dst = a_bf + i;
    } else {
        size_t j = i - (size_t)M * K;
        src = w + j;
        dst = w_bf + j;
    }
    float4 v0 = *(const float4*)(src);
    float4 v1 = *(const float4*)(src + 4);
    bf16x8_t o;
    o[0] = (__bf16)v0.x; o[1] = (__bf16)v0.y; o[2] = (__bf16)v0.z; o[3] = (__bf16)v0.w;
    o[4] = (__bf16)v1.x; o[5] = (__bf16)v1.y; o[6] = (__bf16)v1.z; o[7] = (__bf16)v1.w;
    *(bf16x8_t*)dst = o;
}

// ---------------- bf16 GEMM, 256x256 tile, 8-phase counted-vmcnt pipeline ----
__global__ __launch_bounds__(512, 1) void gemm_bt(const __bf16* __restrict__ A,
                                                  const __bf16* __restrict__ B,
                                                  float* __restrict__ C) {
    // [buf][0=A,1=B][row][col]; row stride 64 bf16 = 128 B = 8 chunks of 16 B.
    // LDS slot (row, chunk c) holds global chunk c ^ (row & 7)  (both-sides involution).
    __shared__ __bf16 lds[2][2][256][BK];   // 128 KiB

    const int tid = threadIdx.x;
    const int lane = tid & 63;
    const int quad = lane >> 4;
    const int l16 = lane & 15;
    const int sa = l16 & 7;            // read-side swizzle key (= frag row & 7)
    const int wave = tid >> 6;         // 8 waves, 2(M) x 4(N)
    const int wm = wave >> 2;
    const int wn = wave & 3;

    const int bm = blockIdx.y * BM;
    const int bn = blockIdx.x * BN;

    // staging per-thread geometry
    const int c8 = tid & 7;            // 16B chunk within a row
    const int r8 = (tid >> 3) & 7;     // dst row & 7 for every stage pattern
    const int scol = (c8 ^ r8) << 3;   // pre-swizzled global source column (elems)
    const int arow = tid >> 3;         // 0..63
    const int bq64 = ((tid >> 8) << 6);// 0 or 64
    const int brow = (tid >> 3) & 31;  // 0..31

    f32x4_t acc[8][4] = {};

#define STAGE_A(buf, mh, k0)                                                        \
  do {                                                                              \
    _Pragma("unroll") for (int r_ = 0; r_ < 2; ++r_) {                              \
      int row_ = r_ * 128 + (mh) * 64 + arow;                                       \
      __builtin_amdgcn_global_load_lds(                                             \
          (const __attribute__((address_space(1))) unsigned int*)(                  \
              A + (size_t)(bm + row_) * K + (k0) + scol),                           \
          (__attribute__((address_space(3))) unsigned int*)(&lds[buf][0][row_][c8 * 8]), \
          16, 0, 0);                                                                \
    }                                                                               \
  } while (0)

#define STAGE_B(buf, nh, k0)                                                        \
  do {                                                                              \
    _Pragma("unroll") for (int r_ = 0; r_ < 2; ++r_) {                              \
      int row_ = r_ * 128 + bq64 + (nh) * 32 + brow;                                \
      __builtin_amdgcn_global_load_lds(                                             \
          (const __attribute__((address_space(1))) unsigned int*)(                  \
              B + (size_t)(bn + row_) * K + (k0) + scol),                           \
          (__attribute__((address_space(3))) unsigned int*)(&lds[buf][1][row_][c8 * 8]), \
          16, 0, 0);                                                                \
    }                                                                               \
  } while (0)

#define LOAD_A(buf, mh)                                                             \
  do {                                                                              \
    _Pragma("unroll") for (int i_ = 0; i_ < 4; ++i_) {                              \
      int row_ = wm * 128 + (mh) * 64 + i_ * 16 + l16;                              \
      _Pragma("unroll") for (int ks_ = 0; ks_ < 2; ++ks_)                           \
        a[i_][ks_] = *(const bf16x8_t*)(&lds[buf][0][row_][((ks_ * 4 + quad) ^ sa) << 3]); \
    }                                                                               \
  } while (0)

#define LOAD_B(buf, nh, bv)                                                         \
  do {                                                                              \
    _Pragma("unroll") for (int j_ = 0; j_ < 2; ++j_) {                              \
      int row_ = wn * 64 + (nh) * 32 + j_ * 16 + l16;                               \
      _Pragma("unroll") for (int ks_ = 0; ks_ < 2; ++ks_)                           \
        bv[j_][ks_] = *(const bf16x8_t*)(&lds[buf][1][row_][((ks_ * 4 + quad) ^ sa) << 3]); \
    }                                                                               \
  } while (0)

#define MFMA_Q(mh, nh, bv)                                                          \
  do {                                                                              \
    __builtin_amdgcn_s_setprio(1);                                                  \
    _Pragma("unroll") for (int i_ = 0; i_ < 4; ++i_)                                \
      _Pragma("unroll") for (int j_ = 0; j_ < 2; ++j_) {                            \
        acc[(mh) * 4 + i_][(nh) * 2 + j_] = __builtin_amdgcn_mfma_f32_16x16x32_bf16( \
            a[i_][0], bv[j_][0], acc[(mh) * 4 + i_][(nh) * 2 + j_], 0, 0, 0);       \
        acc[(mh) * 4 + i_][(nh) * 2 + j_] = __builtin_amdgcn_mfma_f32_16x16x32_bf16( \
            a[i_][1], bv[j_][1], acc[(mh) * 4 + i_][(nh) * 2 + j_], 0, 0, 0);       \
      }                                                                             \
    __builtin_amdgcn_s_setprio(0);                                                  \
  } while (0)

#define FENCE() asm volatile("" ::: "memory")
#define BAR()   do { FENCE(); __builtin_amdgcn_s_barrier(); FENCE(); } while (0)
#define LGKM0() asm volatile("s_waitcnt lgkmcnt(0)" ::: "memory")
#define VMCNT(n_) asm volatile("s_waitcnt vmcnt(" #n_ ")" ::: "memory")

    // Prologue: tile0 fully + tile1.{u1,u4}. vmcnt(4) = first 8 of 12 loads landed
    // = all of tile0.
    STAGE_A(0, 0, 0);      // t0.u1
    STAGE_B(0, 0, 0);      // t0.u2
    STAGE_B(0, 1, 0);      // t0.u4
    STAGE_A(0, 1, 0);      // t0.u3
    STAGE_A(1, 0, BK);     // t1.u1
    STAGE_B(1, 1, BK);     // t1.u4
    VMCNT(4);
    BAR();

    bf16x8_t a[4][2], b0[2][2], b1[2][2];

    for (int it = 0; it < 8; ++it) {
        const int kE = it * 128;
        const int kO = kE + 64;
        int kP2 = kE + 128; if (kP2 > K - BK) kP2 = K - BK;   // clamp: garbage into
        int kP3 = kE + 192; if (kP3 > K - BK) kP3 = K - BK;   // dead regions, in-bounds

        // ph1: E q(0,0)
        LOAD_A(0, 0); LOAD_B(0, 0, b0);
        STAGE_B(1, 0, kO);
        BAR(); LGKM0();
        MFMA_Q(0, 0, b0);
        BAR();

        // ph2: E q(0,1)
        LOAD_B(0, 1, b1);
        STAGE_A(1, 1, kO);
        BAR(); LGKM0();
        MFMA_Q(0, 1, b1);
        BAR();

        // ph3: E q(1,1)
        LOAD_A(0, 1);
        STAGE_A(0, 0, kP2);
        BAR(); LGKM0();
        MFMA_Q(1, 1, b1);
        BAR();

        // ph4: E q(1,0); gate for tile O
        STAGE_B(0, 1, kP2);
        BAR();
        MFMA_Q(1, 0, b0);
        VMCNT(4);
        BAR();

        // ph5: O q(0,0)
        LOAD_A(1, 0); LOAD_B(1, 0, b0);
        STAGE_A(0, 1, kP2);
        BAR(); LGKM0();
        MFMA_Q(0, 0, b0);
        BAR();

        // ph6: O q(0,1)
        LOAD_B(1, 1, b1);
        STAGE_B(0, 0, kP2);
        BAR(); LGKM0();
        MFMA_Q(0, 1, b1);
        BAR();

        // ph7: O q(1,1)
        LOAD_A(1, 1);
        STAGE_A(1, 0, kP3);
        BAR(); LGKM0();
        MFMA_Q(1, 1, b1);
        BAR();

        // ph8: O q(1,0); gate for tile E+2
        STAGE_B(1, 1, kP3);
        BAR();
        MFMA_Q(1, 0, b0);
        VMCNT(4);
        BAR();
    }

    // C/D layout (verified m89/m91): col = lane&15, row = quad*4 + reg.
    const int crow0 = bm + wm * 128 + quad * 4;
    const int ccol0 = bn + wn * 64 + l16;
#pragma unroll
    for (int i_ = 0; i_ < 8; ++i_)
#pragma unroll
      for (int j_ = 0; j_ < 4; ++j_)
#pragma unroll
        for (int r_ = 0; r_ < 4; ++r_)
          C[(size_t)(crow0 + i_ * 16 + r_) * N + (ccol0 + j_ * 16)] = acc[i_][j_][r_];

#undef STAGE_A
#undef STAGE_B
#undef LOAD_A
#undef LOAD_B
#undef MFMA_Q
#undef FENCE
#undef BAR
#undef LGKM0
#undef VMCNT
}

extern "C" void kernel_launch(void* const* d_in, const int* in_sizes, int n_in,
                              void* d_out, int out_size, void* d_ws, size_t ws_size,
                              hipStream_t stream) {
    const float* in_f32 = (const float*)d_in[0];   // [M,K]
    const float* w_f32  = (const float*)d_in[1];   // [N,K]
    float* out = (float*)d_out;                     // [M,N]

    __bf16* A_bf = (__bf16*)d_ws;
    __bf16* W_bf = A_bf + (size_t)M * K;

    cvt_f32_bf16<<<((size_t)(M + N) * K) / (8 * 256), 256, 0, stream>>>(in_f32, w_f32, A_bf, W_bf);

    dim3 grid(N / BN, M / BM);   // (16, 32) = 512 blocks, 1 block/CU (128 KiB LDS)
    gemm_bt<<<grid, 512, 0, stream>>>(A_bf, W_bf, out);
}

// Round 2
// 218.827 us; speedup vs baseline: 1.0801x; 1.0151x over previous
//
#include <hip/hip_runtime.h>
#include <hip/hip_bf16.h>

// out[s,b,o] = sum_h in[s,b,h] * w[o,h]
// A = [M=8192, K=1024] fp32, W = [N=4096, K=1024] fp32 (B^T layout), C = [M,N] fp32.
//
// Round 3 -> 4: single-barrier phases. Round 3's {reads -> BAR -> lgkm0 -> MFMA -> BAR}
// lockstepped all 8 waves, strictly alternating LDS-drain and MFMA windows
// (MfmaUtil 33.6%, dur = serial sum of the two). New phase body is
// {STAGE | ds_reads | MFMA} -> [vmcnt gate] -> BAR: the compiler interleaves reads
// and MFMAs with fine lgkmcnt, and waves desync within the phase so one wave's
// MFMAs cover another's LDS drain.
//
// Hazard ledger (1 barrier per phase, E = even tile buf0, O = odd tile buf1;
// units u1=A.mh0 u2=B.nh0 u3=A.mh1 u4=B.nh1; reads complete before the reader's
// consuming MFMA inside the same phase, barriers are collective so all waves
// occupy the same phase interval):
//   ph1 E.q(0,0) reads A0,B0  stages O.u2    last read prev ph5  (>=4 barriers)
//   ph2 E.q(0,1) reads B1     stages O.u3    last read prev ph7  (>=3 barriers)
//   ph3 E.q(1,1) reads A1     stages E+2.u1  last read ph1       (2 barriers)
//   ph4 E.q(1,0) reads -      stages E+2.u4  last read ph2       (2 barriers)  GATE vmcnt(4)
//   ph5 O.q(0,0) reads A0,B0  stages E+2.u3  last read ph3       (2 barriers)
//   ph6 O.q(0,1) reads B1     stages E+2.u2  last read ph1       (>=4 barriers)
//   ph7 O.q(1,1) reads A1     stages E+3.u1  last read ph5       (2 barriers)
//   ph8 O.q(1,0) reads -      stages E+3.u4  last read ph6       (2 barriers)  GATE vmcnt(4)
// At each gate the next tile's 4 units are positions 3..6-from-last in issue order,
// so vmcnt(4) (2 units still in flight) guarantees them landed; the barrier after the
// gate publishes all waves' gates before any wave reads the tile. Tail iterations
// clamp stage k0 to the last tile (garbage into dead regions, always in-bounds).

typedef __bf16 bf16x8_t __attribute__((ext_vector_type(8)));
typedef float f32x4_t __attribute__((ext_vector_type(4)));

constexpr int M = 8192;
constexpr int N = 4096;
constexpr int K = 1024;
constexpr int BM = 256;
constexpr int BN = 256;
constexpr int BK = 64;

// ---------------- fp32 -> bf16 convert, both tensors in one launch ----------
__global__ __launch_bounds__(256) void cvt_f32_bf16(const float* __restrict__ a,
                                                    const float* __restrict__ w,
                                                    __bf16* __restrict__ a_bf,
                                                    __bf16* __restrict__ w_bf) {
    size_t i = ((size_t)blockIdx.x * 256 + threadIdx.x) * 8;
    const float* src;
    __bf16* dst;
    if (i < (size_t)M * K) {
        src = a + i;
        dst = a_bf + i;
    } else {
        size_t j = i - (size_t)M * K;
        src = w + j;
        dst = w_bf + j;
    }
    float4 v0 = *(const float4*)(src);
    float4 v1 = *(const float4*)(src + 4);
    bf16x8_t o;
    o[0] = (__bf16)v0.x; o[1] = (__bf16)v0.y; o[2] = (__bf16)v0.z; o[3] = (__bf16)v0.w;
    o[4] = (__bf16)v1.x; o[5] = (__bf16)v1.y; o[6] = (__bf16)v1.z; o[7] = (__bf16)v1.w;
    *(bf16x8_t*)dst = o;
}

// ---------------- bf16 GEMM, 256x256 tile, 8-phase / 1-barrier pipeline ------
__global__ __launch_bounds__(512, 1) void gemm_bt(const __bf16* __restrict__ A,
                                                  const __bf16* __restrict__ B,
                                                  float* __restrict__ C) {
    // [buf][0=A,1=B][row][col]; row stride 64 bf16 = 128 B = 8 chunks of 16 B.
    // LDS slot (row, chunk c) holds global chunk c ^ (row & 7)  (both-sides involution).
    __shared__ __bf16 lds[2][2][256][BK];   // 128 KiB

    const int tid = threadIdx.x;
    const int lane = tid & 63;
    const int quad = lane >> 4;
    const int l16 = lane & 15;
    const int sa = l16 & 7;            // read-side swizzle key (= frag row & 7)
    const int wave = tid >> 6;         // 8 waves, 2(M) x 4(N)
    const int wm = wave >> 2;
    const int wn = wave & 3;

    const int bm = blockIdx.y * BM;
    const int bn = blockIdx.x * BN;

    // staging per-thread geometry
    const int c8 = tid & 7;            // 16B chunk within a row
    const int r8 = (tid >> 3) & 7;     // dst row & 7 for every stage pattern
    const int scol = (c8 ^ r8) << 3;   // pre-swizzled global source column (elems)
    const int arow = tid >> 3;         // 0..63
    const int bq64 = ((tid >> 8) << 6);// 0 or 64
    const int brow = (tid >> 3) & 31;  // 0..31

    f32x4_t acc[8][4] = {};

#define STAGE_A(buf, mh, k0)                                                        \
  do {                                                                              \
    _Pragma("unroll") for (int r_ = 0; r_ < 2; ++r_) {                              \
      int row_ = r_ * 128 + (mh) * 64 + arow;                                       \
      __builtin_amdgcn_global_load_lds(                                             \
          (const __attribute__((address_space(1))) unsigned int*)(                  \
              A + (size_t)(bm + row_) * K + (k0) + scol),                           \
          (__attribute__((address_space(3))) unsigned int*)(&lds[buf][0][row_][c8 * 8]), \
          16, 0, 0);                                                                \
    }                                                                               \
  } while (0)

#define STAGE_B(buf, nh, k0)                                                        \
  do {                                                                              \
    _Pragma("unroll") for (int r_ = 0; r_ < 2; ++r_) {                              \
      int row_ = r_ * 128 + bq64 + (nh) * 32 + brow;                                \
      __builtin_amdgcn_global_load_lds(                                             \
          (const __attribute__((address_space(1))) unsigned int*)(                  \
              B + (size_t)(bn + row_) * K + (k0) + scol),                           \
          (__attribute__((address_space(3))) unsigned int*)(&lds[buf][1][row_][c8 * 8]), \
          16, 0, 0);                                                                \
    }                                                                               \
  } while (0)

#define LOAD_A(buf, mh)                                                             \
  do {                                                                              \
    _Pragma("unroll") for (int i_ = 0; i_ < 4; ++i_) {                              \
      int row_ = wm * 128 + (mh) * 64 + i_ * 16 + l16;                              \
      _Pragma("unroll") for (int ks_ = 0; ks_ < 2; ++ks_)                           \
        a[i_][ks_] = *(const bf16x8_t*)(&lds[buf][0][row_][((ks_ * 4 + quad) ^ sa) << 3]); \
    }                                                                               \
  } while (0)

#define LOAD_B(buf, nh, bv)                                                         \
  do {                                                                              \
    _Pragma("unroll") for (int j_ = 0; j_ < 2; ++j_) {                              \
      int row_ = wn * 64 + (nh) * 32 + j_ * 16 + l16;                               \
      _Pragma("unroll") for (int ks_ = 0; ks_ < 2; ++ks_)                           \
        bv[j_][ks_] = *(const bf16x8_t*)(&lds[buf][1][row_][((ks_ * 4 + quad) ^ sa) << 3]); \
    }                                                                               \
  } while (0)

#define MFMA_Q(mh, nh, bv)                                                          \
  do {                                                                              \
    __builtin_amdgcn_s_setprio(1);                                                  \
    _Pragma("unroll") for (int i_ = 0; i_ < 4; ++i_)                                \
      _Pragma("unroll") for (int j_ = 0; j_ < 2; ++j_) {                            \
        acc[(mh) * 4 + i_][(nh) * 2 + j_] = __builtin_amdgcn_mfma_f32_16x16x32_bf16( \
            a[i_][0], bv[j_][0], acc[(mh) * 4 + i_][(nh) * 2 + j_], 0, 0, 0);       \
        acc[(mh) * 4 + i_][(nh) * 2 + j_] = __builtin_amdgcn_mfma_f32_16x16x32_bf16( \
            a[i_][1], bv[j_][1], acc[(mh) * 4 + i_][(nh) * 2 + j_], 0, 0, 0);       \
      }                                                                             \
    __builtin_amdgcn_s_setprio(0);                                                  \
  } while (0)

#define FENCE() asm volatile("" ::: "memory")
#define BAR()   do { FENCE(); __builtin_amdgcn_s_barrier(); FENCE(); } while (0)
#define VMCNT(n_) asm volatile("s_waitcnt vmcnt(" #n_ ")" ::: "memory")

    // Prologue: tile0 fully + tile1.{u1,u4}. vmcnt(4) = first 8 of 12 loads landed
    // = all of tile0.
    STAGE_A(0, 0, 0);      // t0.u1
    STAGE_B(0, 0, 0);      // t0.u2
    STAGE_B(0, 1, 0);      // t0.u4
    STAGE_A(0, 1, 0);      // t0.u3
    STAGE_A(1, 0, BK);     // t1.u1
    STAGE_B(1, 1, BK);     // t1.u4
    VMCNT(4);
    BAR();

    bf16x8_t a[4][2], b0[2][2], b1[2][2];

    for (int it = 0; it < 8; ++it) {
        const int kE = it * 128;
        const int kO = kE + 64;
        int kP2 = kE + 128; if (kP2 > K - BK) kP2 = K - BK;   // clamp: garbage into
        int kP3 = kE + 192; if (kP3 > K - BK) kP3 = K - BK;   // dead regions, in-bounds

        // ph1: E q(0,0)
        STAGE_B(1, 0, kO);
        LOAD_A(0, 0); LOAD_B(0, 0, b0);
        MFMA_Q(0, 0, b0);
        BAR();

        // ph2: E q(0,1)
        STAGE_A(1, 1, kO);
        LOAD_B(0, 1, b1);
        MFMA_Q(0, 1, b1);
        BAR();

        // ph3: E q(1,1)
        STAGE_A(0, 0, kP2);
        LOAD_A(0, 1);
        MFMA_Q(1, 1, b1);
        BAR();

        // ph4: E q(1,0); gate for tile O
        STAGE_B(0, 1, kP2);
        MFMA_Q(1, 0, b0);
        VMCNT(4);
        BAR();

        // ph5: O q(0,0)
        STAGE_A(0, 1, kP2);
        LOAD_A(1, 0); LOAD_B(1, 0, b0);
        MFMA_Q(0, 0, b0);
        BAR();

        // ph6: O q(0,1)
        STAGE_B(0, 0, kP2);
        LOAD_B(1, 1, b1);
        MFMA_Q(0, 1, b1);
        BAR();

        // ph7: O q(1,1)
        STAGE_A(1, 0, kP3);
        LOAD_A(1, 1);
        MFMA_Q(1, 1, b1);
        BAR();

        // ph8: O q(1,0); gate for tile E+2
        STAGE_B(1, 1, kP3);
        MFMA_Q(1, 0, b0);
        VMCNT(4);
        BAR();
    }

    // C/D layout (verified m89/m91): col = lane&15, row = quad*4 + reg.
    const int crow0 = bm + wm * 128 + quad * 4;
    const int ccol0 = bn + wn * 64 + l16;
#pragma unroll
    for (int i_ = 0; i_ < 8; ++i_)
#pragma unroll
      for (int j_ = 0; j_ < 4; ++j_)
#pragma unroll
        for (int r_ = 0; r_ < 4; ++r_)
          C[(size_t)(crow0 + i_ * 16 + r_) * N + (ccol0 + j_ * 16)] = acc[i_][j_][r_];

#undef STAGE_A
#undef STAGE_B
#undef LOAD_A
#undef LOAD_B
#undef MFMA_Q
#undef FENCE
#undef BAR
#undef VMCNT
}

extern "C" void kernel_launch(void* const* d_in, const int* in_sizes, int n_in,
                              void* d_out, int out_size, void* d_ws, size_t ws_size,
                              hipStream_t stream) {
    const float* in_f32 = (const float*)d_in[0];   // [M,K]
    const float* w_f32  = (const float*)d_in[1];   // [N,K]
    float* out = (float*)d_out;                     // [M,N]

    __bf16* A_bf = (__bf16*)d_ws;
    __bf16* W_bf = A_bf + (size_t)M * K;

    cvt_f32_bf16<<<((size_t)(M + N) * K) / (8 * 256), 256, 0, stream>>>(in_f32, w_f32, A_bf, W_bf);

    dim3 grid(N / BN, M / BM);   // (16, 32) = 512 blocks, 1 block/CU (128 KiB LDS)
    gemm_bt<<<grid, 512, 0, stream>>>(A_bf, W_bf, out);
}